// Round 11
// baseline (753.876 us; speedup 1.0000x reference)
//
#include <hip/hip_runtime.h>

// ---------------------------------------------------------------------------
// GRU_13030930776564: bidirectional GRU, B=64, L=1024, DI=D=DO=256 (fp32 io).
//   R11: P1 ELIMINATED by weight-product fusion (associativity):
//       XX = inputs @ (Wi@Wx) + (Wi_b@Wx + Wx_b)
//       XR = inputs @ (Wi@Ux) + (Wi_b@Ux + Ux_b + Wr_b)
//       XU = inputs @ (Wi@Rx) + (Wi_b@Rx + Rx_b + Wu_b)
//   prep: tiny kernel (grid 25) computes the three 256x256 f32 products W'
//       and fused biases b' into workspace (~100 MFLOP, VALU).
//   P2': gemm_p3 — merged 3-GEMM (grid 1536, matrix = bid>>9) reading
//       inputs f32 directly (register-staged strips, R6 prefetch), W' f32
//       preloaded as bf16 fragments, bf16 out.
//   R : EXACT R8 int8-MFMA recurrence (460 us, absmax-neutral; frozen —
//       R2-R5/R9 schedule/TLP/conflict/pre-barrier levers all measured dead).
//   F : gemm_f — out = Hf@Wo + Hb@Wo + Wo_b (MFMA linearity, DMA staging).
// ws layout (u16, E = 64*1024*256): XX | XR | XU | Hf | Hb
//   W'/b' live at the head of the Hf region (f32) — consumed by gemm_p3
//   BEFORE gru_rec overwrites Hf (same-stream ordering).
// ---------------------------------------------------------------------------

typedef float   f32x4 __attribute__((ext_vector_type(4)));
typedef short   s16x8 __attribute__((ext_vector_type(8)));
typedef int     i32x4 __attribute__((ext_vector_type(4)));
typedef unsigned int u32;
typedef unsigned short u16;

#define LDP  264   // padded row stride for At staging (u16 elems)

__device__ __forceinline__ u16 f2bf(float x) {
    u32 u = __float_as_uint(x);
    return (u16)((u + 0x7FFFu + ((u >> 16) & 1u)) >> 16);   // RNE, inputs never NaN
}
__device__ __forceinline__ float bflo(u32 u) { return __uint_as_float(u << 16); }
__device__ __forceinline__ float bfhi(u32 u) { return __uint_as_float(u & 0xFFFF0000u); }
__device__ __forceinline__ float bf2f(u16 v) { return __uint_as_float((u32)v << 16); }

__device__ __forceinline__ float sigm(float z) {
    float e = __builtin_amdgcn_exp2f(z * -1.44269504f);
    return __builtin_amdgcn_rcpf(1.0f + e);
}
__device__ __forceinline__ float tanhfast(float y) {
    float e = __builtin_amdgcn_exp2f(y * 2.88539008f);     // e^(2y)
    return 1.0f - 2.0f * __builtin_amdgcn_rcpf(1.0f + e);  // handles +/-inf saturation
}

__device__ __forceinline__ void bar_lgkm() {
    asm volatile("s_waitcnt lgkmcnt(0)" ::: "memory");
    __builtin_amdgcn_s_barrier();
    asm volatile("" ::: "memory");
}
__device__ __forceinline__ void bar_only() {
    asm volatile("" ::: "memory");
    __builtin_amdgcn_s_barrier();
    asm volatile("" ::: "memory");
}

#define GLD_LDS16(g, l) __builtin_amdgcn_global_load_lds( \
    (const __attribute__((address_space(1))) unsigned int*)(g), \
    (__attribute__((address_space(3))) unsigned int*)(l), 16, 0, 0)

// ---------------------------------------------------------------------------
// prep: W'_m = Wi @ {Wx,Ux,Rx} (f32), b'_m = Wi_b @ {..} + fused biases.
// Grid 25 x 256 thr: blocks 0..23 = (matrix m = b>>3, strip s = b&7, 32 rows);
// block 24 = the three 256-wide bias rows. Thread = one output column.
// ---------------------------------------------------------------------------
__global__ __launch_bounds__(256, 2)
void prep(const float* __restrict__ Wi_w, const float* __restrict__ Wi_b,
          const float* __restrict__ Wx_w, const float* __restrict__ Wx_b,
          const float* __restrict__ Ux_w, const float* __restrict__ Ux_b,
          const float* __restrict__ Rx_w, const float* __restrict__ Rx_b,
          const float* __restrict__ Wr_b, const float* __restrict__ Wu_b,
          float* __restrict__ WP, float* __restrict__ BP)
{
    const int b = (int)blockIdx.x, n = (int)threadIdx.x;
    if (b < 24) {
        const int m = b >> 3, s = b & 7;
        const float* W = (m == 0) ? Wx_w : ((m == 1) ? Ux_w : Rx_w);
        float acc[32];
        #pragma unroll
        for (int r = 0; r < 32; ++r) acc[r] = 0.f;
        for (int k = 0; k < 256; ++k) {
            const float wv = W[k * 256 + n];                 // coalesced across lanes
            const float* wi = Wi_w + (s * 32) * 256 + k;     // lane-uniform (scalar)
            #pragma unroll
            for (int r = 0; r < 32; ++r) acc[r] = fmaf(wi[r * 256], wv, acc[r]);
        }
        float* dst = WP + m * 65536 + (s * 32) * 256 + n;
        #pragma unroll
        for (int r = 0; r < 32; ++r) dst[r * 256] = acc[r];
    } else {
        #pragma unroll
        for (int m = 0; m < 3; ++m) {
            const float* W = (m == 0) ? Wx_w : ((m == 1) ? Ux_w : Rx_w);
            float acc = (m == 0) ? Wx_b[n]
                      : ((m == 1) ? Ux_b[n] + Wr_b[n] : Rx_b[n] + Wu_b[n]);
            for (int k = 0; k < 256; ++k) acc = fmaf(Wi_b[k], W[k * 256 + n], acc);
            BP[m * 256 + n] = acc;
        }
    }
}

// ---------------------------------------------------------------------------
// gemm_p3: merged 3-GEMM from f32 inputs. grid 1536 (m = bid>>9, s0 = bid&511).
// Register-staged f32 strips (R6 prefetch: strip s+1 loads issued between LDS
// staging and MFMAs of strip s), W' f32 -> bf16 fragments, bf16 out.
// ---------------------------------------------------------------------------
__global__ __launch_bounds__(256, 2)
void gemm_p3(const float* __restrict__ A, const float* __restrict__ WP,
             const float* __restrict__ BP,
             u16* __restrict__ C0, u16* __restrict__ C1, u16* __restrict__ C2)
{
    __shared__ u16 At[32 * LDP];
    const int tid  = threadIdx.x;
    const int lane = tid & 63, wv = tid >> 6;
    const int quad = lane >> 4, n16 = lane & 15;

    const int m  = (int)blockIdx.x >> 9;
    const int s0 = (int)blockIdx.x & 511;
    const float* W  = WP + m * 65536;
    const float* b1 = BP + m * 256;
    u16* C = (m == 0) ? C0 : ((m == 1) ? C1 : C2);

    s16x8 bw[4][8];
    #pragma unroll
    for (int nt = 0; nt < 4; ++nt) {
        const int col = wv * 64 + nt * 16 + n16;
        #pragma unroll
        for (int kt = 0; kt < 8; ++kt) {
            const int kb0 = kt * 32 + quad * 8;
            s16x8 f;
            #pragma unroll
            for (int j = 0; j < 8; ++j) f[j] = (short)f2bf(W[(kb0 + j) * 256 + col]);
            bw[nt][kt] = f;
        }
    }

    const int arow = tid >> 3, kb = (tid & 7) * 32;
    float av[32];

    auto load_strip = [&](int ss) __attribute__((always_inline)) {
        const float4* p = (const float4*)(A + (long)(ss * 32 + arow) * 256 + kb);
        #pragma unroll
        for (int i = 0; i < 8; ++i) {
            float4 v = p[i];
            av[i*4+0] = v.x; av[i*4+1] = v.y; av[i*4+2] = v.z; av[i*4+3] = v.w;
        }
    };

    load_strip(s0);

    for (int s = s0; s < 2048; ) {
        bar_only();    // previous strip's MFMA reads of At complete (no vm drain)
        {
            u16 tmp[32];
            #pragma unroll
            for (int i = 0; i < 32; ++i) tmp[i] = f2bf(av[i]);
            s16x8* dst = (s16x8*)&At[arow * LDP + kb];
            #pragma unroll
            for (int i = 0; i < 4; ++i) dst[i] = *(const s16x8*)&tmp[i * 8];
        }
        bar_lgkm();    // At visible (lgkm only)

        const int snext = s + 512;
        if (snext < 2048) load_strip(snext);   // prefetch: hides under MFMAs

        f32x4 acc[2][4];
        #pragma unroll
        for (int mt = 0; mt < 2; ++mt)
            #pragma unroll
            for (int nt = 0; nt < 4; ++nt) acc[mt][nt] = f32x4{0.f, 0.f, 0.f, 0.f};
        #pragma unroll
        for (int kt = 0; kt < 8; ++kt) {
            const int ko = kt * 32 + quad * 8;
            const s16x8 a0 = *(const s16x8*)&At[(n16) * LDP + ko];
            const s16x8 a1 = *(const s16x8*)&At[(16 + n16) * LDP + ko];
            #pragma unroll
            for (int nt = 0; nt < 4; ++nt) {
                acc[0][nt] = __builtin_amdgcn_mfma_f32_16x16x32_bf16(a0, bw[nt][kt], acc[0][nt], 0, 0, 0);
                acc[1][nt] = __builtin_amdgcn_mfma_f32_16x16x32_bf16(a1, bw[nt][kt], acc[1][nt], 0, 0, 0);
            }
        }

        #pragma unroll
        for (int nt = 0; nt < 4; ++nt) {
            const int col = wv * 64 + nt * 16 + n16;
            const float bias = b1[col];
            #pragma unroll
            for (int mt = 0; mt < 2; ++mt) {
                const int row0 = s * 32 + mt * 16 + quad * 4;
                #pragma unroll
                for (int r = 0; r < 4; ++r) {
                    const float v = acc[mt][nt][r] + bias;
                    C[(long)(row0 + r) * 256 + col] = f2bf(v);
                }
            }
        }
        s = snext;
    }
}

// ---------------------------------------------------------------------------
// F: out = Hf@Wo + Hb@Wo + Wo_b (f32 out). MFMA linearity; both bf16
// operands staged via global_load_lds with the proven swizzle. 32KB LDS.
// ---------------------------------------------------------------------------
__global__ __launch_bounds__(256, 2)
void gemm_f(const u16* __restrict__ Hf, const u16* __restrict__ Hb,
            const float* __restrict__ W, const float* __restrict__ bias,
            float* __restrict__ out)
{
    __shared__ u16 At[2][32 * 256];     // [mat] 2 x 16 KiB, linear
    const int tid  = threadIdx.x;
    const int lane = tid & 63, wv = tid >> 6;
    const int quad = lane >> 4, n16 = lane & 15;

    s16x8 bw[4][8];
    #pragma unroll
    for (int nt = 0; nt < 4; ++nt) {
        const int col = wv * 64 + nt * 16 + n16;
        #pragma unroll
        for (int kt = 0; kt < 8; ++kt) {
            const int kb0 = kt * 32 + quad * 8;
            s16x8 f;
            #pragma unroll
            for (int j = 0; j < 8; ++j) f[j] = (short)f2bf(W[(kb0 + j) * 256 + col]);
            bw[nt][kt] = f;
        }
    }

    u32 myL[4];
    #pragma unroll
    for (int r = 0; r < 4; ++r) {
        const u32 p = ((u32)(wv * 4 + r) * 64 + (u32)lane) * 16;
        myL[r] = p ^ (((p >> 9) & 7u) << 4);
    }
    const u32 key   = ((u32)(n16 & 7)) << 4;
    const u32 base0 = (u32)n16 * 512 + (u32)quad * 16;
    const u32 base1 = base0 + 16 * 512;

    auto stage = [&](int ss) __attribute__((always_inline)) {
        const char* f = (const char*)(Hf + (long)ss * 32 * 256);
        const char* b = (const char*)(Hb + (long)ss * 32 * 256);
        #pragma unroll
        for (int r = 0; r < 4; ++r)
            GLD_LDS16(f + myL[r], (char*)&At[0][0] + (u32)(wv * 4 + r) * 1024);
        #pragma unroll
        for (int r = 0; r < 4; ++r)
            GLD_LDS16(b + myL[r], (char*)&At[1][0] + (u32)(wv * 4 + r) * 1024);
    };

    const int s0 = (int)blockIdx.x;
    stage(s0);

    for (int s = s0; s < 2048; s += 512) {
        asm volatile("s_waitcnt vmcnt(0)" ::: "memory");
        bar_only();                              // DMA landed in all waves

        const char* atf = (const char*)&At[0][0];
        const char* atb = (const char*)&At[1][0];
        f32x4 acc[2][4];
        #pragma unroll
        for (int mt = 0; mt < 2; ++mt)
            #pragma unroll
            for (int nt = 0; nt < 4; ++nt) acc[mt][nt] = f32x4{0.f, 0.f, 0.f, 0.f};
        #pragma unroll
        for (int kt = 0; kt < 8; ++kt) {
            const s16x8 f0 = *(const s16x8*)(atf + (((base0 + (u32)kt * 64) ^ key)));
            const s16x8 f1 = *(const s16x8*)(atf + (((base1 + (u32)kt * 64) ^ key)));
            const s16x8 g0 = *(const s16x8*)(atb + (((base0 + (u32)kt * 64) ^ key)));
            const s16x8 g1 = *(const s16x8*)(atb + (((base1 + (u32)kt * 64) ^ key)));
            #pragma unroll
            for (int nt = 0; nt < 4; ++nt) {
                acc[0][nt] = __builtin_amdgcn_mfma_f32_16x16x32_bf16(f0, bw[nt][kt], acc[0][nt], 0, 0, 0);
                acc[1][nt] = __builtin_amdgcn_mfma_f32_16x16x32_bf16(f1, bw[nt][kt], acc[1][nt], 0, 0, 0);
                acc[0][nt] = __builtin_amdgcn_mfma_f32_16x16x32_bf16(g0, bw[nt][kt], acc[0][nt], 0, 0, 0);
                acc[1][nt] = __builtin_amdgcn_mfma_f32_16x16x32_bf16(g1, bw[nt][kt], acc[1][nt], 0, 0, 0);
            }
        }

        #pragma unroll
        for (int nt = 0; nt < 4; ++nt) {
            const int col = wv * 64 + nt * 16 + n16;
            const float bv = bias[col];
            #pragma unroll
            for (int mt = 0; mt < 2; ++mt) {
                const int row0 = s * 32 + mt * 16 + quad * 4;
                #pragma unroll
                for (int r = 0; r < 4; ++r)
                    out[(long)(row0 + r) * 256 + col] = acc[mt][nt][r] + bv;
            }
        }

        const int snext = s + 512;
        if (snext < 2048) {
            bar_only();                          // all waves' At reads done (WAR)
            stage(snext);
        }
    }
}

// ---------------------------------------------------------------------------
// Recurrence — EXACT R8 code (best measured: 460 us, absmax-neutral int8).
// 64 blocks x 512 threads. Wave w owns h-cols [w*32,w*32+32), both gates.
// mfma_i32_16x16x64_i8: 16 MFMAs + 4 ds_read_b128 per wave per step; h fp32
// in regs, int8 (scale 127, |h|<1 structural) in LDS; W per-column int8
// (one-time in-kernel quant). hb8 16B-aligned, parity stride 320B.
// One lgkm-only barrier per step; Hg store + x prefetch stay in flight.
// ---------------------------------------------------------------------------
__global__ __launch_bounds__(512, 2)
void gru_rec(const u16* __restrict__ XX, const u16* __restrict__ XR, const u16* __restrict__ XU,
             const float* __restrict__ Wr, const float* __restrict__ Wu,
             u16* __restrict__ Hf, u16* __restrict__ Hb)
{
    __shared__ __attribute__((aligned(16))) char hb8[2][2 * 320];  // [buf][parity*320+col]
    __shared__ float sdq[8][2][32];       // dequant scale [wave][gate][col]

    const int tid  = threadIdx.x;
    const int lane = tid & 63, wave = tid >> 6;
    const int quad = lane >> 4, n16 = lane & 15;
    const int wg  = blockIdx.x;
    const int dir = wg >> 5;             // 0 fwd, 1 bwd
    const int b0  = (wg & 31) * 2;       // two batches: b0, b0+1
    const int c0  = wave * 32;

    // ---- preload + per-column int8 quantize: aw[g][nt][kt] (B-operand) ----
    i32x4 aw[2][2][4];
    #pragma unroll
    for (int g = 0; g < 2; ++g) {
        const float* Wg = g ? Wu : Wr;
        #pragma unroll
        for (int nt = 0; nt < 2; ++nt) {
            const int col = c0 + nt * 16 + n16;
            float wv64[64];
            float amax = 0.f;
            #pragma unroll
            for (int kt = 0; kt < 4; ++kt)
                #pragma unroll
                for (int j = 0; j < 16; ++j) {
                    const float w = Wg[(kt * 64 + quad * 16 + j) * 256 + col];
                    wv64[kt * 16 + j] = w;
                    amax = fmaxf(amax, fabsf(w));
                }
            // column amax spans the 4 quads (lane ^16, ^32) -> butterfly max
            amax = fmaxf(amax, __shfl_xor(amax, 16));
            amax = fmaxf(amax, __shfl_xor(amax, 32));
            const float inv = 127.f / amax;
            #pragma unroll
            for (int kt = 0; kt < 4; ++kt) {
                u32 b[4];
                #pragma unroll
                for (int d = 0; d < 4; ++d) {
                    u32 v = 0;
                    #pragma unroll
                    for (int e = 0; e < 4; ++e) {
                        const int qi = (int)__builtin_rintf(wv64[kt * 16 + d * 4 + e] * inv);
                        v |= ((u32)(qi & 255u)) << (8 * e);
                    }
                    b[d] = v;
                }
                aw[g][nt][kt] = (i32x4){(int)b[0], (int)b[1], (int)b[2], (int)b[3]};
            }
            if (quad == 0) sdq[wave][g][nt * 16 + n16] = amax * (1.0f / 16129.f); // amax/127^2
        }
    }

    // elementwise identity: one (seq, col) per lane
    const int  eseq = lane >> 5;                 // 0..1  (acc reg index)
    const int  ecl  = lane & 31;                 // 0..31
    const int  ntb  = ecl >> 4;                  // which n-tile holds this col
    const int  gcol = c0 + ecl;                  // global h column
    const long xrow = (long)(b0 + eseq) * 1024;  // row base within [B*L]
    float hprev = 0.0f;

    for (int i = tid; i < 2 * 320; i += 512) hb8[0][i] = 0;   // h(0) = 0

    u16* const Hg = dir ? Hb : Hf;

    u16 cxx, cxr, cxu;
    {
        const long off = (xrow + (dir ? 1023 : 0)) * 256 + gcol;
        cxx = XX[off]; cxr = XR[off]; cxu = XU[off];
    }
    __syncthreads();
    const float srq = sdq[wave][0][ecl];
    const float suq = sdq[wave][1][ecl];

    auto stepbody = [&](int step, int pb) __attribute__((always_inline)) {
        const int t = dir ? 1023 - step : step;
        int sn = step + 1; if (sn > 1023) sn = 1023;
        const int tn = dir ? 1023 - sn : sn;

        // prefetch next step's x (full step of latency slack, counted vmcnt)
        const long offn = (xrow + tn) * 256 + gcol;
        const u16 nxx = XX[offn], nxr = XR[offn], nxu = XU[offn];

        // ---- int8 matvecs: 4 ds_read_b128 + 16 MFMAs ----
        const char* hin = &hb8[pb][0] + (n16 & 1) * 320;
        i32x4 a00 = (i32x4){0,0,0,0}, a01 = a00, a10 = a00, a11 = a00;
        #pragma unroll
        for (int kt = 0; kt < 4; ++kt) {
            const i32x4 hv = *(const i32x4*)(hin + kt * 64 + quad * 16);
            a00 = __builtin_amdgcn_mfma_i32_16x16x64_i8(hv, aw[0][0][kt], a00, 0, 0, 0);
            a01 = __builtin_amdgcn_mfma_i32_16x16x64_i8(hv, aw[0][1][kt], a01, 0, 0, 0);
            a10 = __builtin_amdgcn_mfma_i32_16x16x64_i8(hv, aw[1][0][kt], a10, 0, 0, 0);
            a11 = __builtin_amdgcn_mfma_i32_16x16x64_i8(hv, aw[1][1][kt], a11, 0, 0, 0);
        }

        // ---- in-lane select + dequant ----
        const int pri = ntb ? (eseq ? a01[1] : a01[0]) : (eseq ? a00[1] : a00[0]);
        const int pui = ntb ? (eseq ? a11[1] : a11[0]) : (eseq ? a10[1] : a10[0]);
        const float pr = (float)pri * srq;
        const float pu = (float)pui * suq;

        // ---- elementwise: exactly one (seq, col) per lane ----
        const float rr   = sigm(pr + bf2f(cxr));
        const float uu   = sigm(pu + bf2f(cxu));
        const float cand = tanhfast(rr * hprev + bf2f(cxx));
        hprev = cand + uu * (hprev - cand);

        // |hprev| < 1 -> rint(h*127) in [-127,127], no clamp needed
        hb8[pb ^ 1][eseq * 320 + gcol] = (char)(int)__builtin_rintf(hprev * 127.f);
        Hg[(xrow + t) * 256 + gcol]    = f2bf(hprev);   // persist bf16 (fire & forget)

        cxx = nxx; cxr = nxr; cxu = nxu;
        bar_lgkm();                                     // hb8[pb^1] visible; NO vmcnt drain
    };

    for (int sp = 0; sp < 512; ++sp) {
        stepbody(sp * 2,     0);
        stepbody(sp * 2 + 1, 1);
    }
}

// ---------------------------------------------------------------------------
extern "C" void kernel_launch(void* const* d_in, const int* in_sizes, int n_in,
                              void* d_out, int out_size, void* d_ws, size_t ws_size,
                              hipStream_t stream)
{
    const float* inputs = (const float*)d_in[0];
    const float* Wi_w = (const float*)d_in[1];
    const float* Wi_b = (const float*)d_in[2];
    const float* Wx_w = (const float*)d_in[3];
    const float* Wx_b = (const float*)d_in[4];
    const float* Ux_w = (const float*)d_in[5];
    const float* Ux_b = (const float*)d_in[6];
    const float* Rx_w = (const float*)d_in[7];
    const float* Rx_b = (const float*)d_in[8];
    const float* Wr_w = (const float*)d_in[9];
    const float* Wr_b = (const float*)d_in[10];
    const float* Wu_w = (const float*)d_in[11];
    const float* Wu_b = (const float*)d_in[12];
    const float* Wo_w = (const float*)d_in[13];
    const float* Wo_b = (const float*)d_in[14];

    const long E = 64L * 1024 * 256;
    u16* XX = (u16*)d_ws;
    u16* XR = XX + E;
    u16* XU = XR + E;
    u16* Hf = XU + E;
    u16* Hb = Hf + E;
    // W'/b' scratch: head of the Hf region (f32). Consumed by gemm_p3, which
    // completes before gru_rec writes Hf (same-stream ordering).
    float* WP = (float*)Hf;              // 3 * 65536 f32 = 768 KB
    float* BP = WP + 3 * 65536;          // 3 * 256 f32

    // prep: W'_m = Wi @ {Wx,Ux,Rx};  b'_m = Wi_b @ {..} + fused biases
    hipLaunchKernelGGL(prep, dim3(25), dim3(256), 0, stream,
                       Wi_w, Wi_b, Wx_w, Wx_b, Ux_w, Ux_b, Rx_w, Rx_b,
                       Wr_b, Wu_b, WP, BP);
    // P2' (fused, P1 eliminated): XX/XR/XU = inputs @ W'_m + b'_m
    hipLaunchKernelGGL(gemm_p3, dim3(1536), dim3(256), 0, stream,
                       inputs, WP, BP, XX, XR, XU);
    // R: the sequential scan (both directions concurrently, 64 WGs)
    hipLaunchKernelGGL(gru_rec, dim3(64), dim3(512), 0, stream,
                       (const u16*)XX, (const u16*)XR, (const u16*)XU, Wr_w, Wu_w, Hf, Hb);
    // F: out = Hf@Wo + Hb@Wo + Wo_b
    hipLaunchKernelGGL(gemm_f, dim3(512), dim3(256), 0, stream,
                       (const u16*)Hf, (const u16*)Hb, Wo_w, Wo_b, (float*)d_out);
}